// Round 1
// baseline (553.914 us; speedup 1.0000x reference)
//
#include <hip/hip_runtime.h>
#include <math.h>

#define D 2048
#define NS 8
#define BTOT 16384

// ---- d_out layout (floats): read[B,D] | attn[B,8] | alpha | new_state[8,D] | new_fast[8,D]
#define ATTN_OFF  ((size_t)BTOT * D)
#define ALPHA_OFF (ATTN_OFF + (size_t)BTOT * NS)
#define STATE_OFF (ALPHA_OFF + 1)
#define FAST_OFF  (STATE_OFF + (size_t)NS * D)

// ---- ws layout (float offsets)
#define WS_SM    0         // 16384  : state+fast
#define WS_KP    16384     // 16384  : keys @ Wr
#define WS_KPP   32768     // 262144 : Kp partials (16 d-chunks)
#define WS_GS    294912    // 16384  : G @ Sm
#define WS_P     311296    // 16384  : attn.T @ (h+nm)
#define WS_HWC   327680    // 16384  : h . wc_h per row
#define WS_LB    344064    // 8      : keys @ br
#define WS_SWC   344072    // 8      : Sm @ wc_r
#define WS_G     344080    // 73     : G[64] | colsum[8] | addsum[1]
#define WS_ALPHA 344153    // 1
#define WS_PPART 344160    // NC*16384 : P partials

static __device__ __forceinline__ float4 f4fma(float s, float4 a, float4 c) {
  c.x += s * a.x; c.y += s * a.y; c.z += s * a.z; c.w += s * a.w; return c;
}

// ---- Z: Sm = state + fast; zero the atomic accumulators
__global__ void kZ(const float* __restrict__ st, const float* __restrict__ fa,
                   float* __restrict__ sm, float* __restrict__ gall) {
  int i = blockIdx.x * 256 + threadIdx.x;
  sm[i] = st[i] + fa[i];
  if (blockIdx.x == 0 && threadIdx.x < 73) gall[threadIdx.x] = 0.f;
}

// ---- A: Kp partials over d-chunks.  Kp[s][e] = sum_d keys[s][d] * Wr[d][e]
__global__ void __launch_bounds__(256) kA(const float* __restrict__ keys,
                                          const float* __restrict__ Wr,
                                          float* __restrict__ kpp) {
  int ec = blockIdx.x, dc = blockIdx.y, t = threadIdx.x;
  int e = ec * 256 + t;
  float acc[NS] = {0.f,0.f,0.f,0.f,0.f,0.f,0.f,0.f};
  int d0 = dc * 128;
  for (int d = d0; d < d0 + 128; ++d) {
    float wv = Wr[(size_t)d * D + e];
#pragma unroll
    for (int s = 0; s < NS; ++s) acc[s] += keys[s * D + d] * wv;
  }
#pragma unroll
  for (int s = 0; s < NS; ++s) kpp[(size_t)(dc * NS + s) * D + e] = acc[s];
}

// ---- B: reduce Kp partials
__global__ void kB(const float* __restrict__ kpp, float* __restrict__ kp) {
  int i = blockIdx.x * 256 + threadIdx.x;  // < 16384
  float sum = 0.f;
#pragma unroll
  for (int dc = 0; dc < 16; ++dc) sum += kpp[dc * 16384 + i];
  kp[i] = sum;
}

// ---- C: lbias[s] = keys[s].br ;  Swc[s] = Sm[s].wc_r
__global__ void __launch_bounds__(256) kC(const float* __restrict__ keys,
                                          const float* __restrict__ br,
                                          const float* __restrict__ Wc,
                                          const float* __restrict__ sm,
                                          float* __restrict__ lb, float* __restrict__ swc) {
  int t = threadIdx.x;
  float aL[NS] = {0.f,0.f,0.f,0.f,0.f,0.f,0.f,0.f};
  float aS[NS] = {0.f,0.f,0.f,0.f,0.f,0.f,0.f,0.f};
  for (int idx = t; idx < D; idx += 256) {
    float brv = br[idx];
    float wcr = Wc[D + idx];
#pragma unroll
    for (int s = 0; s < NS; ++s) {
      aL[s] += keys[s * D + idx] * brv;
      aS[s] += sm[s * D + idx] * wcr;
    }
  }
#pragma unroll
  for (int off = 32; off > 0; off >>= 1) {
#pragma unroll
    for (int s = 0; s < NS; ++s) {
      aL[s] += __shfl_down(aL[s], off);
      aS[s] += __shfl_down(aS[s], off);
    }
  }
  __shared__ float red[4 * 16];
  int lane = t & 63, wid = t >> 6;
  if (lane == 0) {
#pragma unroll
    for (int s = 0; s < NS; ++s) { red[wid * 16 + s] = aL[s]; red[wid * 16 + 8 + s] = aS[s]; }
  }
  __syncthreads();
  if (t < 16) {
    float v = red[t] + red[16 + t] + red[32 + t] + red[48 + t];
    if (t < 8) lb[t] = v; else swc[t - 8] = v;
  }
}

// ---- 1: per-row logits -> softmax -> attn ; also h.wc_h
__global__ void __launch_bounds__(256) k1(const float* __restrict__ h, const float* __restrict__ Wc,
                                          const float* __restrict__ kp, const float* __restrict__ lb,
                                          float* __restrict__ attn, float* __restrict__ hwc) {
  int b = blockIdx.x, t = threadIdx.x;
  const float4* hr = (const float4*)(h + (size_t)b * D);
  float4 ha = hr[t], hb = hr[t + 256];
  float acc[9];
  const float4* kp4 = (const float4*)kp;
#pragma unroll
  for (int s = 0; s < NS; ++s) {
    float4 ka = kp4[s * 512 + t], kb = kp4[s * 512 + 256 + t];
    acc[s] = ha.x * ka.x + ha.y * ka.y + ha.z * ka.z + ha.w * ka.w
           + hb.x * kb.x + hb.y * kb.y + hb.z * kb.z + hb.w * kb.w;
  }
  {
    const float4* wc4 = (const float4*)Wc;
    float4 wa = wc4[t], wb = wc4[256 + t];
    acc[8] = ha.x * wa.x + ha.y * wa.y + ha.z * wa.z + ha.w * wa.w
           + hb.x * wb.x + hb.y * wb.y + hb.z * wb.z + hb.w * wb.w;
  }
#pragma unroll
  for (int off = 32; off > 0; off >>= 1) {
#pragma unroll
    for (int v = 0; v < 9; ++v) acc[v] += __shfl_down(acc[v], off);
  }
  __shared__ float red[36];
  int lane = t & 63, wid = t >> 6;
  if (lane == 0) {
#pragma unroll
    for (int v = 0; v < 9; ++v) red[wid * 9 + v] = acc[v];
  }
  __syncthreads();
  if (t == 0) {
    float l[9];
#pragma unroll
    for (int v = 0; v < 9; ++v) l[v] = red[v] + red[9 + v] + red[18 + v] + red[27 + v];
    float lg[8]; float m = -1e30f;
#pragma unroll
    for (int s = 0; s < NS; ++s) { lg[s] = l[s] + lb[s]; m = fmaxf(m, lg[s]); }
    float ex[8]; float sum = 0.f;
#pragma unroll
    for (int s = 0; s < NS; ++s) { ex[s] = expf(lg[s] - m); sum += ex[s]; }
    float inv = 1.f / sum;
    float* ao = attn + (size_t)b * NS;
#pragma unroll
    for (int s = 0; s < NS; ++s) ao[s] = ex[s] * inv;
    hwc[b] = l[8];
  }
}

// ---- 2: read = attn @ Sm (write), P-partials = attn.T @ (h+nm)
__global__ void __launch_bounds__(256) k2(const float* __restrict__ h, const float* __restrict__ nm,
                                          const float* __restrict__ sm, const float* __restrict__ attn,
                                          float* __restrict__ readout, float* __restrict__ ppart,
                                          int rows_per) {
  int t = threadIdx.x;
  int hsel = blockIdx.x & 1, rc = blockIdx.x >> 1;
  int fi = hsel * 256 + t;  // float4 index within a row
  const float4* sm4 = (const float4*)sm;
  float4 S[NS];
#pragma unroll
  for (int s = 0; s < NS; ++s) S[s] = sm4[s * 512 + fi];
  float4 P[NS];
#pragma unroll
  for (int s = 0; s < NS; ++s) P[s] = make_float4(0.f, 0.f, 0.f, 0.f);
  int b0 = rc * rows_per;
  for (int r = 0; r < rows_per; ++r) {
    int b = b0 + r;
    float4 hv = ((const float4*)(h + (size_t)b * D))[fi];
    float4 nv = ((const float4*)(nm + (size_t)b * D))[fi];
    const float4* ar = (const float4*)(attn + (size_t)b * NS);
    float4 a0 = ar[0], a1 = ar[1];
    float av[NS] = {a0.x, a0.y, a0.z, a0.w, a1.x, a1.y, a1.z, a1.w};
    float4 w = make_float4(hv.x + nv.x, hv.y + nv.y, hv.z + nv.z, hv.w + nv.w);
    float4 rd = make_float4(0.f, 0.f, 0.f, 0.f);
#pragma unroll
    for (int s = 0; s < NS; ++s) {
      rd = f4fma(av[s], S[s], rd);
      P[s] = f4fma(av[s], w, P[s]);
    }
    ((float4*)(readout + (size_t)b * D))[fi] = rd;
  }
  float4* pp = (float4*)(ppart + (size_t)blockIdx.x * NS * 1024);
#pragma unroll
  for (int s = 0; s < NS; ++s) pp[s * 256 + t] = P[s];
}

// ---- 2b: attn stats: G = attn.T@attn, colsum, addsum(sigmoid(ctrl0))
__global__ void __launch_bounds__(256) k2b(const float* __restrict__ attn, const float* __restrict__ hwc,
                                           const float* __restrict__ swc, const float* __restrict__ bc,
                                           float* __restrict__ gall) {
  int t = threadIdx.x;
  int b = blockIdx.x * 256 + t;
  const float4* ar = (const float4*)(attn + (size_t)b * NS);
  float4 a0 = ar[0], a1 = ar[1];
  float av[NS] = {a0.x, a0.y, a0.z, a0.w, a1.x, a1.y, a1.z, a1.w};
  float x = hwc[b] + bc[0];
#pragma unroll
  for (int s = 0; s < NS; ++s) x += av[s] * swc[s];
  float add = 1.f / (1.f + expf(-x));
  float v[73];
#pragma unroll
  for (int i = 0; i < NS; ++i)
#pragma unroll
    for (int j = 0; j < NS; ++j) v[i * 8 + j] = av[i] * av[j];
#pragma unroll
  for (int s = 0; s < NS; ++s) v[64 + s] = av[s];
  v[72] = add;
#pragma unroll
  for (int off = 32; off > 0; off >>= 1) {
#pragma unroll
    for (int k = 0; k < 73; ++k) v[k] += __shfl_down(v[k], off);
  }
  __shared__ float red[4 * 73];
  int lane = t & 63, wid = t >> 6;
  if (lane == 0) {
#pragma unroll
    for (int k = 0; k < 73; ++k) red[wid * 73 + k] = v[k];
  }
  __syncthreads();
  if (t < 73) {
    float tot = red[t] + red[73 + t] + red[146 + t] + red[219 + t];
    atomicAdd(&gall[t], tot);
  }
}

// ---- 3: reduce P partials; GS = G @ Sm; alpha
__global__ void k3(const float* __restrict__ ppart, const float* __restrict__ gall,
                   const float* __restrict__ sm, float* __restrict__ p, float* __restrict__ gs,
                   float* __restrict__ alphap, float* __restrict__ alphaout, int NC) {
  int tid = blockIdx.x * 256 + threadIdx.x;
  if (tid < 16384) {
    int s = tid >> 11, e = tid & 2047;
    int hsel = e >> 10, ec = e & 1023;
    float sum = 0.f;
    for (int rc = 0; rc < NC; ++rc)
      sum += ppart[((size_t)(rc * 2 + hsel) * NS + s) * 1024 + ec];
    p[tid] = sum;
  } else {
    int i = tid - 16384;
    int s = i >> 11, e = i & 2047;
    float sum = 0.f;
#pragma unroll
    for (int sp = 0; sp < NS; ++sp) sum += gall[s * 8 + sp] * sm[sp * D + e];
    gs[i] = sum;
  }
  if (tid == 0) {
    float mean = gall[72] * (1.f / (float)BTOT);
    float al = 0.02f + 0.98f * mean;
    al = fminf(fmaxf(al, 0.f), 1.f);
    alphap[0] = al;
    alphaout[0] = al;
  }
}

// ---- 4: delta = P@Wh.T + GS@Wr2.T + colsum*bw ; new_state/new_fast
__global__ void __launch_bounds__(256) k4(const float* __restrict__ Ww, const float* __restrict__ bw,
                                          const float* __restrict__ st, const float* __restrict__ fa,
                                          const float* __restrict__ p, const float* __restrict__ gs,
                                          const float* __restrict__ cs, const float* __restrict__ alphap,
                                          float* __restrict__ outst, float* __restrict__ outfa) {
  int dd = blockIdx.x, t = threadIdx.x;
  const float4* wr = (const float4*)(Ww + (size_t)dd * (2 * D));
  float4 w0 = wr[t], w1 = wr[256 + t], w2 = wr[512 + t], w3 = wr[768 + t];
  const float4* p4 = (const float4*)p;
  const float4* g4 = (const float4*)gs;
  float acc[NS];
#pragma unroll
  for (int s = 0; s < NS; ++s) {
    float4 pa = p4[s * 512 + t], pb = p4[s * 512 + 256 + t];
    float4 ga = g4[s * 512 + t], gb = g4[s * 512 + 256 + t];
    acc[s] = w0.x * pa.x + w0.y * pa.y + w0.z * pa.z + w0.w * pa.w
           + w1.x * pb.x + w1.y * pb.y + w1.z * pb.z + w1.w * pb.w
           + w2.x * ga.x + w2.y * ga.y + w2.z * ga.z + w2.w * ga.w
           + w3.x * gb.x + w3.y * gb.y + w3.z * gb.z + w3.w * gb.w;
  }
#pragma unroll
  for (int off = 32; off > 0; off >>= 1) {
#pragma unroll
    for (int v = 0; v < NS; ++v) acc[v] += __shfl_down(acc[v], off);
  }
  __shared__ float red[32];
  int lane = t & 63, wid = t >> 6;
  if (lane == 0) {
#pragma unroll
    for (int v = 0; v < NS; ++v) red[wid * 8 + v] = acc[v];
  }
  __syncthreads();
  if (t < NS) {
    float tot = red[t] + red[8 + t] + red[16 + t] + red[24 + t];
    float delta = tot + cs[t] * bw[dd];
    float al = alphap[0];
    size_t idx = (size_t)t * D + dd;
    outst[idx] = (1.f - al) * st[idx] + al * delta;
    outfa[idx] = 0.95f * fa[idx] + 0.05f * delta;
  }
}

extern "C" void kernel_launch(void* const* d_in, const int* in_sizes, int n_in,
                              void* d_out, int out_size, void* d_ws, size_t ws_size,
                              hipStream_t stream) {
  const float* h    = (const float*)d_in[0];
  const float* nm   = (const float*)d_in[1];
  const float* keys = (const float*)d_in[2];
  const float* Wr   = (const float*)d_in[3];
  const float* br   = (const float*)d_in[4];
  const float* Wc   = (const float*)d_in[5];
  const float* bc   = (const float*)d_in[6];
  const float* Ww   = (const float*)d_in[7];
  const float* bw   = (const float*)d_in[8];
  const float* st   = (const float*)d_in[9];
  const float* fa   = (const float*)d_in[10];
  float* out = (float*)d_out;
  float* ws  = (float*)d_ws;

  // choose number of row-chunks for P partials based on available workspace
  size_t ws_floats = ws_size / 4;
  int NC = 0;
  for (int c = 256; c >= 1; c >>= 1) {
    if ((size_t)WS_PPART + (size_t)c * 16384 <= ws_floats) { NC = c; break; }
  }
  if (NC == 0) NC = 1;
  int rows_per = BTOT / NC;

  float* sm   = ws + WS_SM;
  float* kp   = ws + WS_KP;
  float* kpp  = ws + WS_KPP;
  float* gsb  = ws + WS_GS;
  float* pb   = ws + WS_P;
  float* hwc  = ws + WS_HWC;
  float* lb   = ws + WS_LB;
  float* swc  = ws + WS_SWC;
  float* gall = ws + WS_G;
  float* alphap = ws + WS_ALPHA;
  float* ppart  = ws + WS_PPART;
  float* attn   = out + ATTN_OFF;

  kZ<<<64, 256, 0, stream>>>(st, fa, sm, gall);
  kA<<<dim3(8, 16), 256, 0, stream>>>(keys, Wr, kpp);
  kB<<<64, 256, 0, stream>>>(kpp, kp);
  kC<<<1, 256, 0, stream>>>(keys, br, Wc, sm, lb, swc);
  k1<<<BTOT, 256, 0, stream>>>(h, Wc, kp, lb, attn, hwc);
  k2<<<2 * NC, 256, 0, stream>>>(h, nm, sm, attn, out, ppart, rows_per);
  k2b<<<64, 256, 0, stream>>>(attn, hwc, swc, bc, gall);
  k3<<<128, 256, 0, stream>>>(ppart, gall, sm, pb, gsb, alphap, out + ALPHA_OFF, NC);
  k4<<<2048, 256, 0, stream>>>(Ww, bw, st, fa, pb, gsb, ws + WS_G + 64, alphap, out + STATE_OFF, out + FAST_OFF);
}

// Round 2
// 493.863 us; speedup vs baseline: 1.1216x; 1.1216x over previous
//
#include <hip/hip_runtime.h>
#include <math.h>

#define D 2048
#define NS 8
#define BTOT 16384

// ---- d_out layout (floats): read[B,D] | attn[B,8] | alpha | new_state[8,D] | new_fast[8,D]
#define ATTN_OFF  ((size_t)BTOT * D)
#define ALPHA_OFF (ATTN_OFF + (size_t)BTOT * NS)
#define STATE_OFF (ALPHA_OFF + 1)
#define FAST_OFF  (STATE_OFF + (size_t)NS * D)

// ---- ws layout (float offsets) — total ~215k floats = 860 KB
#define WS_SM    0         // 16384   : state+fast
#define WS_KPX   16384     // 18432   : [9][2048] rows 0..7 = keys@Wr, row 8 = wc_h
#define WS_GS    34816     // 16384   : G @ Sm
#define WS_PB    51200     // 16384   : P = attn.T @ (h+nm)   (atomic accum)
#define WS_LOG   67584     // 147456  : [B][9] logit partials (atomic accum)
#define WS_LB    215040    // 8       : keys @ br
#define WS_SWC   215048    // 8       : Sm @ wc_r
#define WS_GALL  215056    // 73      : G[64] | colsum[8] | addsum[1]
#define WS_ALPHA 215136    // 1

// ---- Z: init/zero everything + sm = state + fast + copy wc_h into kpx row 8
__global__ void __launch_bounds__(256) kZ(const float* __restrict__ st, const float* __restrict__ fa,
                                          const float* __restrict__ Wc, float* __restrict__ ws) {
  int i = blockIdx.x * 256 + threadIdx.x;
  if (i < 16384) {
    ws[WS_SM + i] = st[i] + fa[i];
  } else if (i < 32768) {
    ws[WS_KPX + (i - 16384)] = 0.f;                       // kpx rows 0..7
  } else if (i < 34816) {
    ws[WS_KPX + 16384 + (i - 32768)] = Wc[i - 32768];     // kpx row 8 = wc_h
  } else if (i < 51200) {
    ws[WS_PB + (i - 34816)] = 0.f;
  } else if (i < 198656) {
    ws[WS_LOG + (i - 51200)] = 0.f;
  } else if (i < 198736) {
    ws[WS_GALL + (i - 198656)] = 0.f;
  }
}

// ---- A: kpx[s][e] += sum_{d in chunk} keys[s][d] * Wr[d][e]   (atomic, 16 adds/addr)
__global__ void __launch_bounds__(256) kA(const float* __restrict__ keys,
                                          const float* __restrict__ Wr,
                                          float* __restrict__ kpx) {
  int e = blockIdx.x * 256 + threadIdx.x;
  int d0 = blockIdx.y * 128;
  float acc[NS] = {0.f,0.f,0.f,0.f,0.f,0.f,0.f,0.f};
  for (int d = d0; d < d0 + 128; ++d) {
    float wv = Wr[(size_t)d * D + e];
#pragma unroll
    for (int s = 0; s < NS; ++s) acc[s] += keys[s * D + d] * wv;
  }
#pragma unroll
  for (int s = 0; s < NS; ++s) atomicAdd(&kpx[s * D + e], acc[s]);
}

// ---- C: lb[s] = keys[s].br ;  swc[s] = Sm[s].wc_r
__global__ void __launch_bounds__(256) kC(const float* __restrict__ keys,
                                          const float* __restrict__ br,
                                          const float* __restrict__ Wc,
                                          const float* __restrict__ sm,
                                          float* __restrict__ lb, float* __restrict__ swc) {
  int t = threadIdx.x;
  float aL[NS] = {0.f,0.f,0.f,0.f,0.f,0.f,0.f,0.f};
  float aS[NS] = {0.f,0.f,0.f,0.f,0.f,0.f,0.f,0.f};
  for (int idx = t; idx < D; idx += 256) {
    float brv = br[idx];
    float wcr = Wc[D + idx];
#pragma unroll
    for (int s = 0; s < NS; ++s) {
      aL[s] += keys[s * D + idx] * brv;
      aS[s] += sm[s * D + idx] * wcr;
    }
  }
#pragma unroll
  for (int off = 32; off > 0; off >>= 1) {
#pragma unroll
    for (int s = 0; s < NS; ++s) {
      aL[s] += __shfl_down(aL[s], off);
      aS[s] += __shfl_down(aS[s], off);
    }
  }
  __shared__ float red[4 * 16];
  int lane = t & 63, wid = t >> 6;
  if (lane == 0) {
#pragma unroll
    for (int s = 0; s < NS; ++s) { red[wid * 16 + s] = aL[s]; red[wid * 16 + 8 + s] = aS[s]; }
  }
  __syncthreads();
  if (t < 16) {
    float v = red[t] + red[16 + t] + red[32 + t] + red[48 + t];
    if (t < 8) lb[t] = v; else swc[t - 8] = v;
  }
}

// ---- 1a: logit partials. Wave owns 64 rows x 256-col chunk; h transposed via LDS so
//          each lane owns a row slice (no shuffles). kpx read as wave-uniform scalar loads.
__global__ void __launch_bounds__(256) k1a(const float* __restrict__ h,
                                           const float* __restrict__ kpx,
                                           float* __restrict__ logits) {
  __shared__ float lds[4][64 * 65];
  int t = threadIdx.x;
  int w = t >> 6, lane = t & 63;
  int wave_id = blockIdx.x * 4 + w;
  int rg = wave_id >> 3, chunk = wave_id & 7;
  int rowbase = rg * 64, colbase = chunk * 256;
  float acc[9] = {0.f,0.f,0.f,0.f,0.f,0.f,0.f,0.f,0.f};
  int c16 = lane & 15, rq = lane >> 4;
  for (int sub = 0; sub < 4; ++sub) {
    int cb = colbase + sub * 64;
    // stage 64 rows x 64 cols (coalesced float4 reads, scalar LDS writes, stride 65)
#pragma unroll
    for (int i = 0; i < 16; ++i) {
      int r = i * 4 + rq;
      float4 v = *(const float4*)(h + (size_t)(rowbase + r) * D + cb + c16 * 4);
      float* dst = &lds[w][r * 65 + c16 * 4];
      dst[0] = v.x; dst[1] = v.y; dst[2] = v.z; dst[3] = v.w;
    }
    __syncthreads();
    const float* hr = &lds[w][lane * 65];
#pragma unroll
    for (int j4 = 0; j4 < 16; ++j4) {
      float h0 = hr[j4 * 4 + 0], h1 = hr[j4 * 4 + 1], h2 = hr[j4 * 4 + 2], h3 = hr[j4 * 4 + 3];
#pragma unroll
      for (int s = 0; s < 9; ++s) {
        const float* kr = kpx + s * D + cb + j4 * 4;   // wave-uniform -> s_load
        acc[s] += h0 * kr[0] + h1 * kr[1] + h2 * kr[2] + h3 * kr[3];
      }
    }
    __syncthreads();
  }
#pragma unroll
  for (int s = 0; s < 9; ++s) atomicAdd(&logits[(size_t)(rowbase + lane) * 9 + s], acc[s]);
}

// ---- 1b: softmax + attn + ctrl sigmoid + G/colsum/addsum reduction (one row per thread)
__global__ void __launch_bounds__(256) k1b(const float* __restrict__ logits,
                                           const float* __restrict__ lb, const float* __restrict__ swc,
                                           const float* __restrict__ bc,
                                           float* __restrict__ attn, float* __restrict__ gall) {
  int t = threadIdx.x;
  int b = blockIdx.x * 256 + t;
  const float* lrow = logits + (size_t)b * 9;
  float lg[NS]; float m = -1e30f;
#pragma unroll
  for (int s = 0; s < NS; ++s) { lg[s] = lrow[s] + lb[s]; m = fmaxf(m, lg[s]); }
  float av[NS]; float sum = 0.f;
#pragma unroll
  for (int s = 0; s < NS; ++s) { av[s] = expf(lg[s] - m); sum += av[s]; }
  float inv = 1.f / sum;
  float* ao = attn + (size_t)b * NS;
#pragma unroll
  for (int s = 0; s < NS; ++s) { av[s] *= inv; ao[s] = av[s]; }
  float x = lrow[8] + bc[0];
#pragma unroll
  for (int s = 0; s < NS; ++s) x += av[s] * swc[s];
  float add = 1.f / (1.f + expf(-x));
  float v[73];
#pragma unroll
  for (int i = 0; i < NS; ++i)
#pragma unroll
    for (int j = 0; j < NS; ++j) v[i * 8 + j] = av[i] * av[j];
#pragma unroll
  for (int s = 0; s < NS; ++s) v[64 + s] = av[s];
  v[72] = add;
#pragma unroll
  for (int off = 32; off > 0; off >>= 1) {
#pragma unroll
    for (int k = 0; k < 73; ++k) v[k] += __shfl_down(v[k], off);
  }
  __shared__ float red[4 * 73];
  int lane = t & 63, wid = t >> 6;
  if (lane == 0) {
#pragma unroll
    for (int k = 0; k < 73; ++k) red[wid * 73 + k] = v[k];
  }
  __syncthreads();
  if (t < 73) {
    float tot = red[t] + red[73 + t] + red[146 + t] + red[219 + t];
    atomicAdd(&gall[t], tot);
  }
}

static __device__ __forceinline__ float4 f4fma(float s, float4 a, float4 c) {
  c.x += s * a.x; c.y += s * a.y; c.z += s * a.z; c.w += s * a.w; return c;
}

// ---- 2: read = attn @ Sm (streamed write), P += attn.T @ (h+nm) (LDS reduce + atomics)
//         grid (8 col-chunks, 64 row-chunks); 4 rows in flight per block iteration.
__global__ void __launch_bounds__(256) k2n(const float* __restrict__ h, const float* __restrict__ nm,
                                           const float* __restrict__ sm, const float* __restrict__ attn,
                                           float* __restrict__ readout, float* __restrict__ pb) {
  __shared__ float4 lp[4][NS][64];
  int t = threadIdx.x;
  int c4 = t & 63, r4 = t >> 6;
  int chunk = blockIdx.x, rc = blockIdx.y;
  int fbase = chunk * 64 + c4;            // float4 index within row [0,512)
  const float4* sm4 = (const float4*)sm;
  float4 S[NS];
#pragma unroll
  for (int s = 0; s < NS; ++s) S[s] = sm4[s * 512 + fbase];
  float4 P[NS];
#pragma unroll
  for (int s = 0; s < NS; ++s) P[s] = make_float4(0.f, 0.f, 0.f, 0.f);
  int rowbase = rc * 256;
  for (int it = 0; it < 64; ++it) {
    int row = rowbase + it * 4 + r4;
    float4 hv = ((const float4*)h)[(size_t)row * 512 + fbase];
    float4 nv = ((const float4*)nm)[(size_t)row * 512 + fbase];
    const float* ar = attn + (size_t)row * NS;   // wave-uniform row
    float4 w = make_float4(hv.x + nv.x, hv.y + nv.y, hv.z + nv.z, hv.w + nv.w);
    float4 rd = make_float4(0.f, 0.f, 0.f, 0.f);
#pragma unroll
    for (int s = 0; s < NS; ++s) {
      float a = ar[s];
      rd = f4fma(a, S[s], rd);
      P[s] = f4fma(a, w, P[s]);
    }
    ((float4*)readout)[(size_t)row * 512 + fbase] = rd;
  }
#pragma unroll
  for (int s = 0; s < NS; ++s) lp[r4][s][c4] = P[s];
  __syncthreads();
  for (int k = t; k < 512; k += 256) {
    int s = k >> 6, c = k & 63;
    float4 a = lp[0][s][c], b = lp[1][s][c], cc = lp[2][s][c], d = lp[3][s][c];
    float4 v = make_float4(a.x + b.x + cc.x + d.x, a.y + b.y + cc.y + d.y,
                           a.z + b.z + cc.z + d.z, a.w + b.w + cc.w + d.w);
    float* dst = pb + s * D + chunk * 256 + c * 4;
    atomicAdd(dst + 0, v.x); atomicAdd(dst + 1, v.y);
    atomicAdd(dst + 2, v.z); atomicAdd(dst + 3, v.w);
  }
}

// ---- 3: GS = G @ Sm ; alpha
__global__ void k3n(const float* __restrict__ gall, const float* __restrict__ sm,
                    float* __restrict__ gs, float* __restrict__ alphap, float* __restrict__ alphaout) {
  int i = blockIdx.x * 256 + threadIdx.x;   // < 16384
  int s = i >> 11, e = i & 2047;
  float sum = 0.f;
#pragma unroll
  for (int sp = 0; sp < NS; ++sp) sum += gall[s * 8 + sp] * sm[sp * D + e];
  gs[i] = sum;
  if (i == 0) {
    float mean = gall[72] * (1.f / (float)BTOT);
    float al = 0.02f + 0.98f * mean;
    al = fminf(fmaxf(al, 0.f), 1.f);
    alphap[0] = al;
    alphaout[0] = al;
  }
}

// ---- 4: delta = P@Wh.T + GS@Wr2.T + colsum*bw ; new_state/new_fast
__global__ void __launch_bounds__(256) k4(const float* __restrict__ Ww, const float* __restrict__ bw,
                                          const float* __restrict__ st, const float* __restrict__ fa,
                                          const float* __restrict__ p, const float* __restrict__ gs,
                                          const float* __restrict__ cs, const float* __restrict__ alphap,
                                          float* __restrict__ outst, float* __restrict__ outfa) {
  int dd = blockIdx.x, t = threadIdx.x;
  const float4* wr = (const float4*)(Ww + (size_t)dd * (2 * D));
  float4 w0 = wr[t], w1 = wr[256 + t], w2 = wr[512 + t], w3 = wr[768 + t];
  const float4* p4 = (const float4*)p;
  const float4* g4 = (const float4*)gs;
  float acc[NS];
#pragma unroll
  for (int s = 0; s < NS; ++s) {
    float4 pa = p4[s * 512 + t], pb2 = p4[s * 512 + 256 + t];
    float4 ga = g4[s * 512 + t], gb = g4[s * 512 + 256 + t];
    acc[s] = w0.x * pa.x + w0.y * pa.y + w0.z * pa.z + w0.w * pa.w
           + w1.x * pb2.x + w1.y * pb2.y + w1.z * pb2.z + w1.w * pb2.w
           + w2.x * ga.x + w2.y * ga.y + w2.z * ga.z + w2.w * ga.w
           + w3.x * gb.x + w3.y * gb.y + w3.z * gb.z + w3.w * gb.w;
  }
#pragma unroll
  for (int off = 32; off > 0; off >>= 1) {
#pragma unroll
    for (int v = 0; v < NS; ++v) acc[v] += __shfl_down(acc[v], off);
  }
  __shared__ float red[32];
  int lane = t & 63, wid = t >> 6;
  if (lane == 0) {
#pragma unroll
    for (int v = 0; v < NS; ++v) red[wid * 8 + v] = acc[v];
  }
  __syncthreads();
  if (t < NS) {
    float tot = red[t] + red[8 + t] + red[16 + t] + red[24 + t];
    float delta = tot + cs[t] * bw[dd];
    float al = alphap[0];
    size_t idx = (size_t)t * D + dd;
    outst[idx] = (1.f - al) * st[idx] + al * delta;
    outfa[idx] = 0.95f * fa[idx] + 0.05f * delta;
  }
}

extern "C" void kernel_launch(void* const* d_in, const int* in_sizes, int n_in,
                              void* d_out, int out_size, void* d_ws, size_t ws_size,
                              hipStream_t stream) {
  const float* h    = (const float*)d_in[0];
  const float* nm   = (const float*)d_in[1];
  const float* keys = (const float*)d_in[2];
  const float* Wr   = (const float*)d_in[3];
  const float* br   = (const float*)d_in[4];
  const float* Wc   = (const float*)d_in[5];
  const float* bc   = (const float*)d_in[6];
  const float* Ww   = (const float*)d_in[7];
  const float* bw   = (const float*)d_in[8];
  const float* st   = (const float*)d_in[9];
  const float* fa   = (const float*)d_in[10];
  float* out = (float*)d_out;
  float* ws  = (float*)d_ws;

  float* sm     = ws + WS_SM;
  float* kpx    = ws + WS_KPX;
  float* gsb    = ws + WS_GS;
  float* pb     = ws + WS_PB;
  float* logits = ws + WS_LOG;
  float* lb     = ws + WS_LB;
  float* swc    = ws + WS_SWC;
  float* gall   = ws + WS_GALL;
  float* alphap = ws + WS_ALPHA;
  float* attn   = out + ATTN_OFF;

  kZ<<<777, 256, 0, stream>>>(st, fa, Wc, ws);
  kA<<<dim3(8, 16), 256, 0, stream>>>(keys, Wr, kpx);
  kC<<<1, 256, 0, stream>>>(keys, br, Wc, sm, lb, swc);
  k1a<<<512, 256, 0, stream>>>(h, kpx, logits);
  k1b<<<64, 256, 0, stream>>>(logits, lb, swc, bc, attn, gall);
  k2n<<<dim3(8, 64), 256, 0, stream>>>(h, nm, sm, attn, out, pb);
  k3n<<<64, 256, 0, stream>>>(gall, sm, gsb, alphap, out + ALPHA_OFF);
  k4<<<2048, 256, 0, stream>>>(Ww, bw, st, fa, pb, gsb, gall + 64, alphap, out + STATE_OFF, out + FAST_OFF);
}